// Round 2
// baseline (1317.939 us; speedup 1.0000x reference)
//
#include <hip/hip_runtime.h>
#include <hip/hip_bf16.h>
#include <math.h>

// ---------------------------------------------------------------------------
// FractalDecoderV8 on MI355X (gfx950)
// bf16 MFMA (16x16x32), fp32 accumulate, fp32 master h kept in VGPRs.
//  - prep: transpose+cast weights to B^T bf16 (lane loads 16B of K per frag)
//  - features: 3 tiny kernels -> feats bf16 [4096][192] (K padded 177->192)
//  - fractal_kernel: 128 blocks x 512 thr; block owns M=32 rows (two 16-row
//    MFMA tiles sharing every weight B-fragment in-register -> halves L2
//    weight traffic vs M=16). h/t intermediates live in LDS (50KB), fp32
//    master h lives in VGPRs (D-fragment lane mapping is step-invariant).
//  - out_gemm: 128x128 MFMA tiles, grid (m-fast, n-slow) so blocks sharing
//    a B n-panel run together (L2/L3 reuse); C-write bound.
// ---------------------------------------------------------------------------

typedef __hip_bfloat16 B16;
typedef __attribute__((ext_vector_type(8))) short bf16x8;   // 8 bf16 = 16 B
typedef __attribute__((ext_vector_type(4))) float f32x4;

#define MFMA16(a, b, c) __builtin_amdgcn_mfma_f32_16x16x32_bf16((a), (b), (c), 0, 0, 0)

__device__ __forceinline__ float gelu_exact(float v) {
  // torch nn.GELU default / jax approximate=False: 0.5*x*(1+erf(x/sqrt(2)))
  return 0.5f * v * (1.0f + erff(v * 0.70710678118654752440f));
}

__device__ __forceinline__ bf16x8 ldg_bf16x8(const B16* p) {
  return *reinterpret_cast<const bf16x8*>(p);
}

// ---------------------------------------------------------------------------
// transpose + cast fp32 [R][C] -> bf16 [C][Rpad], zero-fill rows R..Rpad-1
// grid (Rpad/32, C/32), block (32,8)
// ---------------------------------------------------------------------------
__global__ void transpose_cast(const float* __restrict__ src, B16* __restrict__ dst,
                               int R, int C, int Rpad) {
  __shared__ float tile[32][33];
  const int r0 = blockIdx.x * 32;
  const int c0 = blockIdx.y * 32;
  const int tx = threadIdx.x, ty = threadIdx.y;
#pragma unroll
  for (int i = 0; i < 4; ++i) {
    int r = r0 + ty + i * 8;
    tile[ty + i * 8][tx] = (r < R) ? src[(size_t)r * C + c0 + tx] : 0.0f;
  }
  __syncthreads();
#pragma unroll
  for (int i = 0; i < 4; ++i) {
    int c = c0 + ty + i * 8;
    dst[(size_t)c * Rpad + r0 + tx] = __float2bfloat16(tile[tx][ty + i * 8]);
  }
}

// ---------------------------------------------------------------------------
// Feature kernels -> feats bf16 [4096][192]
// cols: 0=x, 1..48=sin, 49..96=cos, 97..144=hash(12x4), 145..176=z, 177..191=0
// ---------------------------------------------------------------------------
__global__ void freq_sincos_kernel(const float* __restrict__ x, B16* __restrict__ feats) {
  __shared__ float fr[48];
  const int t = threadIdx.x;
  if (t < 48) fr[t] = (float)pow(10.0, (double)t * (4.0 / 47.0));  // logspace(0,4,48)
  __syncthreads();
  int idx = blockIdx.x * 256 + t;        // 4096*48 items, grid=768
  int b = idx / 48, k = idx - b * 48;
  float xv = x[b];
  float c2pi = 6.28318530717958647692f;  // fp32(2*pi), matches jax weak-typed cast
  float arg = (c2pi * xv) * fr[k];
  feats[b * 192 + 1 + k]  = __float2bfloat16(sinf(arg));
  feats[b * 192 + 49 + k] = __float2bfloat16(cosf(arg));
}

__constant__ float RES_TAB[12] = {16.0f, 24.0f, 36.0f, 54.0f, 81.0f, 121.5f,
                                  182.25f, 273.375f, 410.0625f, 615.09375f,
                                  922.640625f, 1383.9609375f};  // 16*1.5^l exact fp32

__global__ void hash_kernel(const float* __restrict__ x, const float* __restrict__ tables,
                            B16* __restrict__ feats) {
  int idx = blockIdx.x * 256 + threadIdx.x;  // 4096*12 items, grid=192
  int b = idx / 12, l = idx - b * 12;
  float xv = x[b];
  float pos = xv * RES_TAB[l];
  float fl = floorf(pos);
  unsigned il = (unsigned)fl;
  unsigned hl = (il * 2654435761u) & 16383u;
  unsigned hr = ((il + 1u) * 2654435761u) & 16383u;
  float tt = pos - fl;
  tt = fminf(fmaxf(tt, 0.0f), 1.0f);
  const float* el = tables + ((size_t)l * 16384 + hl) * 4;
  const float* er = tables + ((size_t)l * 16384 + hr) * 4;
#pragma unroll
  for (int d = 0; d < 4; ++d) {
    float v = (1.0f - tt) * el[d] + tt * er[d];
    feats[b * 192 + 97 + l * 4 + d] = __float2bfloat16(v);
  }
}

__global__ void misc_kernel(const float* __restrict__ x, const float* __restrict__ z,
                            B16* __restrict__ feats) {
  int idx = blockIdx.x * 256 + threadIdx.x;  // 4096*48 items, grid=768
  int b = idx / 48, j = idx - b * 48;
  if (j == 0) {
    feats[b * 192] = __float2bfloat16(x[b]);
  } else if (j <= 32) {
    feats[b * 192 + 144 + j] = __float2bfloat16(z[b * 32 + j - 1]);  // cols 145..176
  } else {
    feats[b * 192 + 144 + j] = __float2bfloat16(0.0f);               // cols 177..191 pad
  }
}

// ---------------------------------------------------------------------------
// Fractal kernel: 128 blocks x 512 threads (8 waves), M=32 rows/block.
// Wave w owns N-slices: IN1/IN2/G2 cols [w*32,w*32+32), G1 cols [w*64,+64).
// Each B-fragment load feeds TWO 16-row M-tiles (in-register reuse) -> L2
// weight traffic = 512KB/block/step * 128 blocks * 64 steps = 4.2GB.
// fp32 master h: hprev[mt][f][j] in VGPRs (D lane-mapping identical every
// step: row=(lane>>4)*4+j, col=w*32+f*16+(lane&15)).
// MFMA 16x16x32 bf16 layouts: A[row=lane&15][k=(lane>>4)*8+j],
// B^T[col=lane&15][k=(lane>>4)*8+j], D[row=(lane>>4)*4+j][col=lane&15].
// ---------------------------------------------------------------------------
__global__ __launch_bounds__(512, 1) void fractal_kernel(
    const B16* __restrict__ feats,    // [4096][192]
    const B16* __restrict__ W1T,      // [256][192]  = W_in1^T (K padded)
    const float* __restrict__ b_in1,  // [256]
    const B16* __restrict__ W2T,      // [256][256]  = W_in2^T
    const float* __restrict__ b_in2,  // [256]
    const B16* __restrict__ Wf1T,     // [512][256]  = W_f1^T
    const float* __restrict__ b_f1,   // [512]
    const B16* __restrict__ Wf2T,     // [256][512]  = W_f2^T
    const float* __restrict__ b_f2,   // [256]
    B16* __restrict__ hout)           // [4096][256]
{
  // +8 bf16 pad: row stride 528B/1040B = 4 (mod 32) dwords -> 2-way (free)
  __shared__ __align__(16) B16 hA[32][264];    // h (bf16 A-operand), 16.9KB
  __shared__ __align__(16) B16 tA[32][520];    // 512-wide intermediate, 33.3KB

  const int tid = threadIdx.x;
  const int w = tid >> 6;        // wave 0..7
  const int lane = tid & 63;
  const int lr = lane & 15;      // A-row / B-col / D-col within 16-tile
  const int lg = lane >> 4;      // k-group 0..3
  const int r0 = blockIdx.x * 32;

  float hprev[2][2][4];          // fp32 master h, this lane's D-elements

  // hoisted biases (col mapping fixed for whole kernel)
  float bias_i1[2], bias_i2[2], bias1[4], bias2[2];
#pragma unroll
  for (int f = 0; f < 2; ++f) {
    bias_i1[f] = b_in1[w * 32 + f * 16 + lr];
    bias_i2[f] = b_in2[w * 32 + f * 16 + lr];
    bias2[f]   = b_f2[w * 32 + f * 16 + lr];
  }
#pragma unroll
  for (int f = 0; f < 4; ++f) bias1[f] = b_f1[w * 64 + f * 16 + lr];

  // ---- IN1: tA[.][0..255] = gelu(feats @ W_in1 + b), K=192, N=256
  {
    f32x4 acc[2][2] = {};
#pragma unroll
    for (int s = 0; s < 6; ++s) {
      bf16x8 a0 = ldg_bf16x8(feats + (r0 + lr) * 192 + s * 32 + lg * 8);
      bf16x8 a1 = ldg_bf16x8(feats + (r0 + 16 + lr) * 192 + s * 32 + lg * 8);
#pragma unroll
      for (int f = 0; f < 2; ++f) {
        bf16x8 b = ldg_bf16x8(W1T + (w * 32 + f * 16 + lr) * 192 + s * 32 + lg * 8);
        acc[0][f] = MFMA16(a0, b, acc[0][f]);
        acc[1][f] = MFMA16(a1, b, acc[1][f]);
      }
    }
#pragma unroll
    for (int f = 0; f < 2; ++f) {
      int col = w * 32 + f * 16 + lr;
#pragma unroll
      for (int mt = 0; mt < 2; ++mt)
#pragma unroll
        for (int j = 0; j < 4; ++j)
          tA[mt * 16 + lg * 4 + j][col] =
              __float2bfloat16(gelu_exact(acc[mt][f][j] + bias_i1[f]));
    }
  }
  __syncthreads();

  // ---- IN2: h = gelu(tA @ W_in2 + b), K=256, N=256 -> hprev (VGPR) + hA
  {
    f32x4 acc[2][2] = {};
#pragma unroll
    for (int s = 0; s < 8; ++s) {
      bf16x8 a0 = ldg_bf16x8(&tA[lr][s * 32 + lg * 8]);
      bf16x8 a1 = ldg_bf16x8(&tA[16 + lr][s * 32 + lg * 8]);
#pragma unroll
      for (int f = 0; f < 2; ++f) {
        bf16x8 b = ldg_bf16x8(W2T + (w * 32 + f * 16 + lr) * 256 + s * 32 + lg * 8);
        acc[0][f] = MFMA16(a0, b, acc[0][f]);
        acc[1][f] = MFMA16(a1, b, acc[1][f]);
      }
    }
#pragma unroll
    for (int f = 0; f < 2; ++f) {
      int col = w * 32 + f * 16 + lr;
#pragma unroll
      for (int mt = 0; mt < 2; ++mt)
#pragma unroll
        for (int j = 0; j < 4; ++j) {
          float v = gelu_exact(acc[mt][f][j] + bias_i2[f]);
          hprev[mt][f][j] = v;
          hA[mt * 16 + lg * 4 + j][col] = __float2bfloat16(v);
        }
    }
  }
  __syncthreads();

  // ---- 64 fractal steps; weights streamed from L2, each frag -> 2 MFMAs
  for (int step = 0; step < 64; ++step) {
    // G1: tA = gelu(hA @ W_f1 + b_f1), K=256, N=512 (wave: 64 cols)
    {
      f32x4 acc[2][4] = {};
#pragma unroll
      for (int s = 0; s < 8; ++s) {
        bf16x8 a0 = ldg_bf16x8(&hA[lr][s * 32 + lg * 8]);
        bf16x8 a1 = ldg_bf16x8(&hA[16 + lr][s * 32 + lg * 8]);
#pragma unroll
        for (int f = 0; f < 4; ++f) {
          bf16x8 b = ldg_bf16x8(Wf1T + (w * 64 + f * 16 + lr) * 256 + s * 32 + lg * 8);
          acc[0][f] = MFMA16(a0, b, acc[0][f]);
          acc[1][f] = MFMA16(a1, b, acc[1][f]);
        }
      }
#pragma unroll
      for (int f = 0; f < 4; ++f) {
        int col = w * 64 + f * 16 + lr;
#pragma unroll
        for (int mt = 0; mt < 2; ++mt)
#pragma unroll
          for (int j = 0; j < 4; ++j)
            tA[mt * 16 + lg * 4 + j][col] =
                __float2bfloat16(gelu_exact(acc[mt][f][j] + bias1[f]));
      }
    }
    __syncthreads();

    // G2: h = 0.5*h + 0.5*tanh(tA @ W_f2 + b_f2), K=512, N=256 (wave: 32 cols)
    {
      f32x4 acc[2][2] = {};
#pragma unroll
      for (int s = 0; s < 16; ++s) {
        bf16x8 a0 = ldg_bf16x8(&tA[lr][s * 32 + lg * 8]);
        bf16x8 a1 = ldg_bf16x8(&tA[16 + lr][s * 32 + lg * 8]);
#pragma unroll
        for (int f = 0; f < 2; ++f) {
          bf16x8 b = ldg_bf16x8(Wf2T + (w * 32 + f * 16 + lr) * 512 + s * 32 + lg * 8);
          acc[0][f] = MFMA16(a0, b, acc[0][f]);
          acc[1][f] = MFMA16(a1, b, acc[1][f]);
        }
      }
#pragma unroll
      for (int f = 0; f < 2; ++f) {
        int col = w * 32 + f * 16 + lr;
#pragma unroll
        for (int mt = 0; mt < 2; ++mt)
#pragma unroll
          for (int j = 0; j < 4; ++j) {
            float u = tanhf(acc[mt][f][j] + bias2[f]);
            float nv = 0.5f * hprev[mt][f][j] + 0.5f * u;  // fp32 master in VGPR
            hprev[mt][f][j] = nv;
            hA[mt * 16 + lg * 4 + j][col] = __float2bfloat16(nv);
          }
      }
    }
    __syncthreads();
  }

  // ---- write final h (bf16) for the output GEMM
  for (int i = tid; i < 32 * 256; i += 512) {
    int r = i >> 8, c = i & 255;
    hout[(r0 + r) * 256 + c] = hA[r][c];
  }
}

// ---------------------------------------------------------------------------
// Output GEMM: C[4096][32000] = A[4096][256](bf16) @ W_out + b_out (fp32 out)
// 128x128 tile, 256 thr (4 waves 2x2), K=256 in 8 chunks, reg-staged LDS,
// +8 bf16 row pad. grid (32, 250): x = m-block (fast) so the 32 blocks
// sharing one B n-panel dispatch together -> B re-reads collapse into L2/L3.
// ---------------------------------------------------------------------------
__global__ __launch_bounds__(256, 1) void out_gemm(
    const B16* __restrict__ A,       // [4096][256]
    const B16* __restrict__ BT,      // [32000][256] = W_out^T
    const float* __restrict__ bias,  // [32000]
    float* __restrict__ C)           // [4096][32000]
{
  __shared__ __align__(16) B16 As[128][40];
  __shared__ __align__(16) B16 Bs[128][40];
  const int tid = threadIdx.x;
  const int m0 = blockIdx.x * 128;
  const int n0 = blockIdx.y * 128;
  const int w = tid >> 6, lane = tid & 63;
  const int lr = lane & 15, lg = lane >> 4;
  const int wm = (w >> 1) * 64, wn = (w & 1) * 64;
  const int sr = tid >> 1;            // staging row 0..127
  const int sk = (tid & 1) * 16;      // k offset 0/16

  f32x4 acc[4][4] = {};
#pragma unroll 1
  for (int kt = 0; kt < 8; ++kt) {
    bf16x8 a0 = ldg_bf16x8(A + (size_t)(m0 + sr) * 256 + kt * 32 + sk);
    bf16x8 a1 = ldg_bf16x8(A + (size_t)(m0 + sr) * 256 + kt * 32 + sk + 8);
    bf16x8 b0 = ldg_bf16x8(BT + (size_t)(n0 + sr) * 256 + kt * 32 + sk);
    bf16x8 b1 = ldg_bf16x8(BT + (size_t)(n0 + sr) * 256 + kt * 32 + sk + 8);
    __syncthreads();  // all waves finished reading LDS of previous chunk
    *reinterpret_cast<bf16x8*>(&As[sr][sk])     = a0;
    *reinterpret_cast<bf16x8*>(&As[sr][sk + 8]) = a1;
    *reinterpret_cast<bf16x8*>(&Bs[sr][sk])     = b0;
    *reinterpret_cast<bf16x8*>(&Bs[sr][sk + 8]) = b1;
    __syncthreads();
    bf16x8 af[4], bfr[4];
#pragma unroll
    for (int i = 0; i < 4; ++i) af[i] = ldg_bf16x8(&As[wm + i * 16 + lr][lg * 8]);
#pragma unroll
    for (int j = 0; j < 4; ++j) bfr[j] = ldg_bf16x8(&Bs[wn + j * 16 + lr][lg * 8]);
#pragma unroll
    for (int i = 0; i < 4; ++i)
#pragma unroll
      for (int j = 0; j < 4; ++j) acc[i][j] = MFMA16(af[i], bfr[j], acc[i][j]);
  }
#pragma unroll
  for (int i = 0; i < 4; ++i)
#pragma unroll
    for (int j = 0; j < 4; ++j) {
      int col = n0 + wn + j * 16 + lr;
      float bv = bias[col];
#pragma unroll
      for (int q = 0; q < 4; ++q) {
        int row = m0 + wm + i * 16 + lg * 4 + q;
        C[(size_t)row * 32000 + col] = acc[i][j][q] + bv;
      }
    }
}

// ---------------------------------------------------------------------------
// host-side launch
// ---------------------------------------------------------------------------
extern "C" void kernel_launch(void* const* d_in, const int* in_sizes, int n_in,
                              void* d_out, int out_size, void* d_ws, size_t ws_size,
                              hipStream_t stream) {
  (void)in_sizes; (void)n_in; (void)out_size; (void)ws_size;
  const float* x      = (const float*)d_in[0];
  const float* z      = (const float*)d_in[1];
  const float* tables = (const float*)d_in[2];
  const float* W_in1  = (const float*)d_in[3];
  const float* b_in1  = (const float*)d_in[4];
  const float* W_in2  = (const float*)d_in[5];
  const float* b_in2  = (const float*)d_in[6];
  const float* W_f1   = (const float*)d_in[7];
  const float* b_f1   = (const float*)d_in[8];
  const float* W_f2   = (const float*)d_in[9];
  const float* b_f2   = (const float*)d_in[10];
  const float* W_out  = (const float*)d_in[11];
  const float* b_out  = (const float*)d_in[12];
  float* out = (float*)d_out;

  char* ws = (char*)d_ws;
  // workspace layout
  B16* W1T   = (B16*)(ws + 0);          //  [256][192]  98304 B
  B16* W2T   = (B16*)(ws + 98304);      //  [256][256] 131072 B
  B16* Wf1T  = (B16*)(ws + 229376);     //  [512][256] 262144 B
  B16* Wf2T  = (B16*)(ws + 491520);     //  [256][512] 262144 B
  B16* feats = (B16*)(ws + 753664);     // [4096][192] 1572864 B
  B16* hbuf  = (B16*)(ws + 2326528);    // [4096][256] 2097152 B
  B16* WoT   = (B16*)(ws + 4423680);    // [32000][256] 16384000 B (~19.9 MB)

  dim3 tb(32, 8);
  transpose_cast<<<dim3(6, 8),    tb, 0, stream>>>(W_in1, W1T, 177, 256, 192);
  transpose_cast<<<dim3(8, 8),    tb, 0, stream>>>(W_in2, W2T, 256, 256, 256);
  transpose_cast<<<dim3(8, 16),   tb, 0, stream>>>(W_f1, Wf1T, 256, 512, 256);
  transpose_cast<<<dim3(16, 8),   tb, 0, stream>>>(W_f2, Wf2T, 512, 256, 512);
  transpose_cast<<<dim3(8, 1000), tb, 0, stream>>>(W_out, WoT, 256, 32000, 256);

  freq_sincos_kernel<<<768, 256, 0, stream>>>(x, feats);
  hash_kernel<<<192, 256, 0, stream>>>(x, tables, feats);
  misc_kernel<<<768, 256, 0, stream>>>(x, z, feats);

  fractal_kernel<<<128, 512, 0, stream>>>(feats, W1T, b_in1, W2T, b_in2,
                                          Wf1T, b_f1, Wf2T, b_f2, hbuf);

  out_gemm<<<dim3(32, 250), 256, 0, stream>>>(hbuf, WoT, b_out, out);
}